// Round 5
// baseline (267.395 us; speedup 1.0000x reference)
//
#include <hip/hip_runtime.h>
#include <cmath>

#define NPTS 131072
#define MTOT 65536
#define NNB  32
#define KKP  15
#define INF  64
#define OUTF 128
#define KCDIM 1920
#define ROWB 3840   // bytes per wfeat row (1920 * 2B)

// LDS layout (fused kernel)
#define META_OFF  122880                // [32][32] float4 = 16 KB
#define LDS_TOTAL 139264
// post-conv reuse of dead wfeat region:
#define PART_OFF  0                     // 6 x 8 KB f32 partials (kq=1..3, mt=0..1)
#define A2_OFF    49152                 // 8 KB bf16 leaky(conv), swizzled
#define A3_OFF    57344                 // 4 KB bf16 raw feats, swizzled

typedef __attribute__((ext_vector_type(8))) __bf16 bf16x8;
typedef __attribute__((ext_vector_type(8))) unsigned short u16x8;
typedef __attribute__((ext_vector_type(4))) float f32x4;
typedef unsigned int u32;

__device__ __forceinline__ float bf2f(u32 v){ return __builtin_bit_cast(float, v<<16); }
__device__ __forceinline__ u32 f2bf(float f){
  u32 u = __builtin_bit_cast(u32, f);
  return (u + 0x7fffu + ((u>>16)&1u)) >> 16;
}
__device__ __forceinline__ float leaky(float v){ return v >= 0.f ? v : 0.01f*v; }

// ---------------- K0: weight repack + bf16 convert ----------------
// bpack: fragment-major kpw. frag(s=0..59, otile=0..7, lr=0..15, lg=0..3) is 16B
// holding kpw[k = s*32+lg*8+j][o = otile*16+lr], j=0..7.
// byte addr = (s*8+otile)*1024 + lr*64 + lg*16.
__global__ __launch_bounds__(256) void k_cvt_67723(
    const float* __restrict__ kpw, const float* __restrict__ wpost,
    const float* __restrict__ wsc, const float* __restrict__ wpre,
    unsigned short* __restrict__ bpack, unsigned short* __restrict__ wpostT,
    unsigned short* __restrict__ wscT, unsigned short* __restrict__ wpreT)
{
  int tid = blockIdx.x * 256 + threadIdx.x;
  if (tid < KCDIM * OUTF) {
    int k = tid >> 7, o = tid & 127;                // consecutive tid -> consecutive o
    int s = k >> 5, kin = k & 31, lg = kin >> 3, j = kin & 7;
    int otile = o >> 4, lr = o & 15;
    bpack[(s*8 + otile)*512 + lr*32 + lg*8 + j] =
        (unsigned short)f2bf(kpw[(size_t)k * OUTF + o]);
    return;
  }
  int t2 = tid - KCDIM * OUTF;
  if (t2 < OUTF * OUTF) {                           // wpostT[out][in]
    int o = t2 / OUTF, i = t2 % OUTF;
    wpostT[t2] = (unsigned short)f2bf(wpost[i * OUTF + o]);
    return;
  }
  int t3 = t2 - OUTF * OUTF;
  if (t3 < OUTF * INF) {                            // wscT[out][in]
    int o = t3 / INF, c = t3 % INF;
    wscT[t3] = (unsigned short)f2bf(wsc[c * OUTF + o]);
    return;
  }
  int t4 = t3 - OUTF * INF;
  if (t4 < OUTF * INF) {                            // wpreT[out][in]
    int o = t4 / INF, c = t4 % INF;
    wpreT[t4] = (unsigned short)f2bf(wpre[c * OUTF + o]);
  }
}

// ---------------- K1: pre layer via MFMA: featbf = leaky(features @ W_pre + b) ----
__global__ __launch_bounds__(256) void k_pre_67723(
    const float* __restrict__ feat, const unsigned short* __restrict__ wpreT,
    const float* __restrict__ bp, unsigned short* __restrict__ featbf)
{
  const int w = threadIdx.x >> 6, l = threadIdx.x & 63, lr = l & 15, lg = l >> 4;
  const int m0 = blockIdx.x * 128 + w * 32;
  f32x4 acc[2][8];
#pragma unroll
  for (int ot = 0; ot < 8; ot++) {
    float bv = bp[ot*16 + lr];
    f32x4 s = {bv, bv, bv, bv};
    acc[0][ot] = s; acc[1][ot] = s;
  }
  bf16x8 af[2][2];
#pragma unroll
  for (int mi = 0; mi < 2; mi++)
#pragma unroll
  for (int ks = 0; ks < 2; ks++) {
    const float* src = feat + (size_t)(m0 + mi*16 + lr) * INF + ks*32 + lg*8;
    float4 f0 = *(const float4*)src, f1 = *(const float4*)(src + 4);
    u16x8 p;
    p[0]=f2bf(f0.x); p[1]=f2bf(f0.y); p[2]=f2bf(f0.z); p[3]=f2bf(f0.w);
    p[4]=f2bf(f1.x); p[5]=f2bf(f1.y); p[6]=f2bf(f1.z); p[7]=f2bf(f1.w);
    af[mi][ks] = __builtin_bit_cast(bf16x8, p);
  }
#pragma unroll
  for (int ks = 0; ks < 2; ks++)
#pragma unroll
  for (int ot = 0; ot < 8; ot++) {
    bf16x8 b = *(const bf16x8*)(wpreT + (size_t)(ot*16 + lr) * INF + ks*32 + lg*8);
    acc[0][ot] = __builtin_amdgcn_mfma_f32_16x16x32_bf16(af[0][ks], b, acc[0][ot], 0,0,0);
    acc[1][ot] = __builtin_amdgcn_mfma_f32_16x16x32_bf16(af[1][ks], b, acc[1][ot], 0,0,0);
  }
#pragma unroll
  for (int mi = 0; mi < 2; mi++)
#pragma unroll
  for (int ot = 0; ot < 8; ot++)
#pragma unroll
  for (int r = 0; r < 4; r++) {
    int m = m0 + mi*16 + lg*4 + r;
    featbf[(size_t)m * OUTF + ot*16 + lr] = (unsigned short)f2bf(leaky(acc[mi][ot][r]));
  }
}

// ---------------- K2: fused KPConv: wfeat (LDS) + barrier-free conv + post + sc ----
// Block = 32 samples, 512 threads (8 waves). Conv: waves = 2 m-tiles x 4-way K
// split; B read directly from L2-resident fragment-major bpack (no staging).
__global__ __launch_bounds__(512) void k_fused_67723(
    const float* __restrict__ points, const float* __restrict__ features,
    const float* __restrict__ kp, const float* __restrict__ bpost,
    const float* __restrict__ bsc, const int* __restrict__ sample_idx,
    const int* __restrict__ nbr, const unsigned short* __restrict__ featbf,
    const unsigned short* __restrict__ bpack, const unsigned short* __restrict__ wpostT,
    const unsigned short* __restrict__ wscT, float* __restrict__ out,
    float inv_ext, int nwg)
{
  extern __shared__ char smem[];
  float4* meta = (float4*)(smem + META_OFF);
  const int t = threadIdx.x, l = t & 63, w = t >> 6, lr = l & 15, lg = l >> 4;
  const int bid = blockIdx.x;
  const int swb = (bid & 7) * (nwg >> 3) + (bid >> 3);   // XCD-contiguous swizzle
  const int m0 = swb * 32;                               // global sample base

  // ---- phase 0: neighbor meta ----
  for (int e = t; e < 1024; e += 512) {
    int s = e >> 5, n = e & 31;
    int gm = m0 + s;
    int sidx = sample_idx[gm];
    int ni = nbr[(size_t)gm * NNB + n];
    bool valid = ni < NPTS;
    int nic = valid ? ni : 0;
    float qx = points[sidx*3], qy = points[sidx*3+1], qz = points[sidx*3+2];
    float dx = points[nic*3] - qx, dy = points[nic*3+1] - qy, dz = points[nic*3+2] - qz;
    if (!valid) dx = 1e9f;
    meta[s*32 + n] = make_float4(dx, dy, dz, __int_as_float(nic * (OUTF*2)));
  }
  __syncthreads();

  // ---- phase A: per wave 4 samples: wfeat[16k x 128c] = w^T @ X  -> LDS ----
  {
    const bool kvalid = lr < KKP;
    const int kk = kvalid ? lr : 0;
    const float kx = kp[kk*3], ky = kp[kk*3+1], kz = kp[kk*3+2];
    const char* fb = (const char*)featbf;
    const f32x4 zero = {0,0,0,0};
    for (int i = 0; i < 4; i++) {
      const int s = w*4 + i;
      float4 mj[8];
#pragma unroll
      for (int j = 0; j < 8; j++) mj[j] = meta[s*32 + lg*8 + j];

      u32 apk[4];
#pragma unroll
      for (int j2 = 0; j2 < 4; j2++) {
        u32 lohi[2];
#pragma unroll
        for (int h = 0; h < 2; h++) {
          float4 m_ = mj[2*j2 + h];
          float ex = m_.x - kx, ey = m_.y - ky, ez = m_.z - kz;
          float d = sqrtf(ex*ex + ey*ey + ez*ez);
          float wv = fmaxf(1.f - d * inv_ext, 0.f);
          lohi[h] = kvalid ? f2bf(wv) : 0u;
        }
        apk[j2] = lohi[0] | (lohi[1] << 16);
      }
      bf16x8 afr = __builtin_bit_cast(bf16x8, apk);
      char* wrow = smem + s * ROWB;
      const int sswz = (s & 7) << 4;

#pragma unroll
      for (int t2 = 0; t2 < 2; t2++) {
        uint2 dj[8];
#pragma unroll
        for (int j = 0; j < 8; j++) {
          u32 off = __builtin_bit_cast(u32, mj[j].w);
          dj[j] = *(const uint2*)(fb + off + t2*128 + lr*8);
        }
        f32x4 D[4];
#pragma unroll
        for (int q = 0; q < 4; q++) {
          u32 b[4];
#pragma unroll
          for (int u = 0; u < 4; u++) {
            u32 w0 = (q < 2) ? dj[2*u].x   : dj[2*u].y;
            u32 w1 = (q < 2) ? dj[2*u+1].x : dj[2*u+1].y;
            b[u] = __builtin_amdgcn_perm(w1, w0, (q & 1) ? 0x07060302u : 0x05040100u);
          }
          D[q] = __builtin_amdgcn_mfma_f32_16x16x32_bf16(
                     afr, __builtin_bit_cast(bf16x8, b), zero, 0,0,0);
        }
#pragma unroll
        for (int r = 0; r < 4; r++) {
          int kr = lg*4 + r;
          if (kr < KKP) {
            uint2 pv;
            pv.x = f2bf(D[0][r]) | (f2bf(D[1][r]) << 16);
            pv.y = f2bf(D[2][r]) | (f2bf(D[3][r]) << 16);
            *(uint2*)(wrow + ((kr*256 + t2*128 + lr*8) ^ sswz)) = pv;
          }
        }
      }
    }
  }
  __syncthreads();

  // ---- conv: barrier-free. wave (mt, kq): rows mt*16.., k-steps kq*15..+15,
  //      all 128 o. B direct from global bpack (1 KB coalesced frag per load).
  const int mt = w & 1, kq = w >> 1;
  const int mrow = mt*16 + lr;
  const char* arow = smem + mrow * ROWB;
  const int aswz = (mrow & 7) << 4;
  const char* bb = (const char*)bpack + (size_t)(kq*15) * 8192 + lr*64 + lg*16;

  f32x4 acc[8];
#pragma unroll
  for (int ot = 0; ot < 8; ot++) acc[ot] = (f32x4){0,0,0,0};

#pragma unroll 3
  for (int si = 0; si < 15; si++) {
    const int s = kq*15 + si;
    bf16x8 af = *(const bf16x8*)(arow + ((s*64 + lg*16) ^ aswz));
    const char* bs = bb + si*8192;
#pragma unroll
    for (int ot = 0; ot < 8; ot++) {
      bf16x8 bfr = *(const bf16x8*)(bs + ot*1024);
      acc[ot] = __builtin_amdgcn_mfma_f32_16x16x32_bf16(af, bfr, acc[ot], 0,0,0);
    }
  }
  __syncthreads();   // all wfeat reads done; LDS region reusable

  // ---- reduction staging: kq>0 waves write f32 partials; a3 staged ----
  if (kq > 0) {
    float* pp = (float*)(smem + PART_OFF + ((kq-1)*2 + mt)*8192);
#pragma unroll
    for (int ot = 0; ot < 8; ot++)
#pragma unroll
    for (int r = 0; r < 4; r++)
      pp[(lg*4 + r)*128 + ot*16 + lr] = acc[ot][r];
  }
  if (t < 256) {
    int r = t >> 3, seg = t & 7;
    int sidx = sample_idx[m0 + r];
    const float* src = features + (size_t)sidx * INF + seg*8;
    float4 f0 = *(const float4*)src, f1 = *(const float4*)(src + 4);
    uint4 pv = make_uint4(f2bf(f0.x) | (f2bf(f0.y) << 16),
                          f2bf(f0.z) | (f2bf(f0.w) << 16),
                          f2bf(f1.x) | (f2bf(f1.y) << 16),
                          f2bf(f1.z) | (f2bf(f1.w) << 16));
    *(uint4*)(smem + A3_OFF + r*128 + ((seg*16) ^ ((r & 7) << 4))) = pv;
  }
  __syncthreads();

  // ---- kq==0 waves: reduce partials, leaky, write a2 bf16 swizzled ----
  if (kq == 0) {
#pragma unroll
    for (int p = 0; p < 3; p++) {
      const float* pp = (const float*)(smem + PART_OFF + (p*2 + mt)*8192);
#pragma unroll
      for (int ot = 0; ot < 8; ot++)
#pragma unroll
      for (int r = 0; r < 4; r++)
        acc[ot][r] += pp[(lg*4 + r)*128 + ot*16 + lr];
    }
    char* a2 = smem + A2_OFF;
#pragma unroll
    for (int ot = 0; ot < 8; ot++)
#pragma unroll
    for (int r = 0; r < 4; r++) {
      int m = mt*16 + lg*4 + r;
      int o = ot*16 + lr;
      *(unsigned short*)(a2 + m*256 + ((o*2) ^ ((m & 15) << 4))) =
          (unsigned short)f2bf(leaky(acc[ot][r]));
    }
  }
  __syncthreads();

  // ---- post (K=128) + shortcut (K=64): waves = (emt, oq), biases in C init ----
  const int oq = w >> 1;                    // o-quarter for epilogue
  const char* a2 = smem + A2_OFF;
  const char* a3 = smem + A3_OFF;
  f32x4 d[2];
#pragma unroll
  for (int ot = 0; ot < 2; ot++) {
    float bv = bpost[oq*32 + ot*16 + lr] + bsc[oq*32 + ot*16 + lr];
    d[ot] = (f32x4){bv, bv, bv, bv};
  }
#pragma unroll
  for (int ks = 0; ks < 4; ks++) {
    bf16x8 af = *(const bf16x8*)(a2 + mrow*256 + ((ks*64 + lg*16) ^ ((mrow & 15) << 4)));
#pragma unroll
    for (int ot = 0; ot < 2; ot++) {
      bf16x8 b = *(const bf16x8*)(wpostT + (size_t)(oq*32 + ot*16 + lr) * OUTF + ks*32 + lg*8);
      d[ot] = __builtin_amdgcn_mfma_f32_16x16x32_bf16(af, b, d[ot], 0,0,0);
    }
  }
#pragma unroll
  for (int ks = 0; ks < 2; ks++) {
    bf16x8 af = *(const bf16x8*)(a3 + mrow*128 + ((ks*64 + lg*16) ^ ((mrow & 7) << 4)));
#pragma unroll
    for (int ot = 0; ot < 2; ot++) {
      bf16x8 b = *(const bf16x8*)(wscT + (size_t)(oq*32 + ot*16 + lr) * INF + ks*32 + lg*8);
      d[ot] = __builtin_amdgcn_mfma_f32_16x16x32_bf16(af, b, d[ot], 0,0,0);
    }
  }
#pragma unroll
  for (int ot = 0; ot < 2; ot++)
#pragma unroll
  for (int r = 0; r < 4; r++) {
    int m = mt*16 + lg*4 + r;
    int o = oq*32 + ot*16 + lr;
    out[(size_t)(m0 + m) * OUTF + o] = leaky(d[ot][r]);
  }
}

extern "C" void kernel_launch(void* const* d_in, const int* in_sizes, int n_in,
                              void* d_out, int out_size, void* d_ws, size_t ws_size,
                              hipStream_t stream)
{
  const float* points   = (const float*)d_in[0];
  const float* features = (const float*)d_in[1];
  const float* W_pre    = (const float*)d_in[2];
  const float* b_pre    = (const float*)d_in[3];
  const float* kpts     = (const float*)d_in[4];
  const float* kpw      = (const float*)d_in[5];
  const float* W_post   = (const float*)d_in[6];
  const float* b_post   = (const float*)d_in[7];
  const float* W_sc     = (const float*)d_in[8];
  const float* b_sc     = (const float*)d_in[9];
  const int* sample_idx = (const int*)d_in[10];
  const int* nbr        = (const int*)d_in[11];
  float* out = (float*)d_out;

  char* ws = (char*)d_ws;
  unsigned short* featbf = (unsigned short*)ws;                 // 33,554,432 B
  unsigned short* bpack  = (unsigned short*)(ws + 33554432);    //    491,520 B
  unsigned short* wpostT = (unsigned short*)(ws + 34045952);    //     32,768 B
  unsigned short* wscT   = (unsigned short*)(ws + 34078720);    //     16,384 B
  unsigned short* wpreT  = (unsigned short*)(ws + 34095104);    //     16,384 B

  double ext = (1.5 / 40.0) / (pow(15.0, 1.0 / 3.0) - 1.0) * 1.5;
  float inv_ext = (float)(1.0 / ext);

  (void)hipFuncSetAttribute((const void*)k_fused_67723,
                            hipFuncAttributeMaxDynamicSharedMemorySize, LDS_TOTAL);

  const int nwg = MTOT / 32;   // 2048
  k_cvt_67723<<<1088, 256, 0, stream>>>(kpw, W_post, W_sc, W_pre, bpack, wpostT, wscT, wpreT);
  k_pre_67723<<<1024, 256, 0, stream>>>(features, wpreT, b_pre, featbf);
  k_fused_67723<<<nwg, 512, LDS_TOTAL, stream>>>(points, features, kpts, b_post, b_sc,
                                                 sample_idx, nbr, featbf, bpack, wpostT,
                                                 wscT, out, inv_ext, nwg);
}

// Round 7
// 173.396 us; speedup vs baseline: 1.5421x; 1.5421x over previous
//
#include <hip/hip_runtime.h>
#include <cmath>

#define NPTS 131072
#define MTOT 65536
#define NNB  32
#define KKP  15
#define INF  64
#define OUTF 128
#define KCDIM 1920
#define WROWB 1920      // bytes per wfeat half-row (15k x 64c x 2B)

// LDS layout (fused kernel): wfeat half 60KB + meta 16KB
#define META_OFF  61440
#define LDS_TOTAL 77824
// post-conv reuse of dead wfeat region:
#define A2_OFF 0        // 32 x 256B bf16 leaky(conv), swizzled
#define A3_OFF 8192     // 32 x 128B bf16 raw feats, swizzled

typedef __attribute__((ext_vector_type(8))) __bf16 bf16x8;
typedef __attribute__((ext_vector_type(8))) unsigned short u16x8;
typedef __attribute__((ext_vector_type(4))) float f32x4;
typedef unsigned int u32;
typedef __attribute__((ext_vector_type(4))) u32 u32x4;

__device__ __forceinline__ u32 f2bf(float f){
  u32 u = __builtin_bit_cast(u32, f);
  return (u + 0x7fffu + ((u>>16)&1u)) >> 16;
}
__device__ __forceinline__ float leaky(float v){ return v >= 0.f ? v : 0.01f*v; }

// ---------------- K0: weight repack + bf16 convert ----------------
// bpack fragment-major: frag(h=0..1, s=0..29, ot=0..7) is 1KB holding
// B[kidx = s*32+lg*8+j][o = ot*16+lr] of K-half h, where kidx maps to kpw
// element (kk = s>>1, c = h*64 + (s&1)*32 + lg*8 + j).
__global__ __launch_bounds__(256) void k_cvt_67723(
    const float* __restrict__ kpw, const float* __restrict__ wpost,
    const float* __restrict__ wsc, const float* __restrict__ wpre,
    unsigned short* __restrict__ bpack, unsigned short* __restrict__ wpostT,
    unsigned short* __restrict__ wscT, unsigned short* __restrict__ wpreT)
{
  int tid = blockIdx.x * 256 + threadIdx.x;
  if (tid < KCDIM * OUTF) {
    int kc = tid >> 7, o = tid & 127;               // consecutive tid -> consecutive o
    int kk = kc >> 7, c = kc & 127;
    int h = c >> 6, cl = c & 63;
    int s = kk*2 + (cl >> 5);
    int rem = cl & 31, lg = rem >> 3, j = rem & 7;
    int ot = o >> 4, lr = o & 15;
    bpack[(size_t)((h*30 + s)*8 + ot)*512 + lr*32 + lg*8 + j] =
        (unsigned short)f2bf(kpw[(size_t)kc * OUTF + o]);
    return;
  }
  int t2 = tid - KCDIM * OUTF;
  if (t2 < OUTF * OUTF) {                           // wpostT[out][in]
    int o = t2 / OUTF, i = t2 % OUTF;
    wpostT[t2] = (unsigned short)f2bf(wpost[i * OUTF + o]);
    return;
  }
  int t3 = t2 - OUTF * OUTF;
  if (t3 < OUTF * INF) {                            // wscT[out][in]
    int o = t3 / INF, c = t3 % INF;
    wscT[t3] = (unsigned short)f2bf(wsc[c * OUTF + o]);
    return;
  }
  int t4 = t3 - OUTF * INF;
  if (t4 < OUTF * INF) {                            // wpreT[out][in]
    int o = t4 / INF, c = t4 % INF;
    wpreT[t4] = (unsigned short)f2bf(wpre[c * OUTF + o]);
  }
}

// ---------------- K1: pre layer via MFMA: featbf = leaky(features @ W_pre + b) ----
__global__ __launch_bounds__(256) void k_pre_67723(
    const float* __restrict__ feat, const unsigned short* __restrict__ wpreT,
    const float* __restrict__ bp, unsigned short* __restrict__ featbf)
{
  const int w = threadIdx.x >> 6, l = threadIdx.x & 63, lr = l & 15, lg = l >> 4;
  const int m0 = blockIdx.x * 128 + w * 32;
  f32x4 acc[2][8];
#pragma unroll
  for (int ot = 0; ot < 8; ot++) {
    float bv = bp[ot*16 + lr];
    f32x4 s = {bv, bv, bv, bv};
    acc[0][ot] = s; acc[1][ot] = s;
  }
  bf16x8 af[2][2];
#pragma unroll
  for (int mi = 0; mi < 2; mi++)
#pragma unroll
  for (int ks = 0; ks < 2; ks++) {
    const float* src = feat + (size_t)(m0 + mi*16 + lr) * INF + ks*32 + lg*8;
    float4 f0 = *(const float4*)src, f1 = *(const float4*)(src + 4);
    u16x8 p;
    p[0]=f2bf(f0.x); p[1]=f2bf(f0.y); p[2]=f2bf(f0.z); p[3]=f2bf(f0.w);
    p[4]=f2bf(f1.x); p[5]=f2bf(f1.y); p[6]=f2bf(f1.z); p[7]=f2bf(f1.w);
    af[mi][ks] = __builtin_bit_cast(bf16x8, p);
  }
#pragma unroll
  for (int ks = 0; ks < 2; ks++)
#pragma unroll
  for (int ot = 0; ot < 8; ot++) {
    bf16x8 b = *(const bf16x8*)(wpreT + (size_t)(ot*16 + lr) * INF + ks*32 + lg*8);
    acc[0][ot] = __builtin_amdgcn_mfma_f32_16x16x32_bf16(af[0][ks], b, acc[0][ot], 0,0,0);
    acc[1][ot] = __builtin_amdgcn_mfma_f32_16x16x32_bf16(af[1][ks], b, acc[1][ot], 0,0,0);
  }
#pragma unroll
  for (int mi = 0; mi < 2; mi++)
#pragma unroll
  for (int ot = 0; ot < 8; ot++)
#pragma unroll
  for (int r = 0; r < 4; r++) {
    int m = m0 + mi*16 + lg*4 + r;
    featbf[(size_t)m * OUTF + ot*16 + lr] = (unsigned short)f2bf(leaky(acc[mi][ot][r]));
  }
}

// ---------------- K2: fused KPConv, c-dim two-phase, 60KB wfeat half in LDS ----
// Block = 32 samples, 512 threads (8 waves), 2 blocks/CU. Per half h:
// phase A (gather+MFMA -> LDS half) / barrier / conv accumulate over K-half.
__global__ __launch_bounds__(512, 4) void k_fused_67723(
    const float* __restrict__ points, const float* __restrict__ features,
    const float* __restrict__ kp, const float* __restrict__ bpost,
    const float* __restrict__ bsc, const int* __restrict__ sample_idx,
    const int* __restrict__ nbr, const unsigned short* __restrict__ featbf,
    const unsigned short* __restrict__ bpack, const unsigned short* __restrict__ wpostT,
    const unsigned short* __restrict__ wscT, float* __restrict__ out,
    float inv_ext, int nwg)
{
  extern __shared__ char smem[];
  float4* meta = (float4*)(smem + META_OFF);
  const int t = threadIdx.x, l = t & 63, w = t >> 6, lr = l & 15, lg = l >> 4;
  const int bid = blockIdx.x;
  const int swb = (bid & 7) * (nwg >> 3) + (bid >> 3);   // XCD-contiguous swizzle
  const int m0 = swb * 32;                               // global sample base

  // ---- phase 0: neighbor meta ----
  for (int e = t; e < 1024; e += 512) {
    int s = e >> 5, n = e & 31;
    int gm = m0 + s;
    int sidx = sample_idx[gm];
    int ni = nbr[(size_t)gm * NNB + n];
    bool valid = ni < NPTS;
    int nic = valid ? ni : 0;
    float qx = points[sidx*3], qy = points[sidx*3+1], qz = points[sidx*3+2];
    float dx = points[nic*3] - qx, dy = points[nic*3+1] - qy, dz = points[nic*3+2] - qz;
    if (!valid) dx = 1e9f;
    meta[s*32 + n] = make_float4(dx, dy, dz, __int_as_float(nic * (OUTF*2)));
  }
  __syncthreads();

  const bool kvalid = lr < KKP;
  const int kk2 = kvalid ? lr : 0;
  const float kx = kp[kk2*3], ky = kp[kk2*3+1], kz = kp[kk2*3+2];
  const char* fb = (const char*)featbf;
  const f32x4 zero = {0,0,0,0};

  f32x4 acc[2] = {{0,0,0,0},{0,0,0,0}};
  const int convswz = (lr & 7) << 4;
  const char* arow0 = smem + lr * WROWB;
  const char* arow1 = smem + (lr + 16) * WROWB;

#pragma unroll
  for (int h = 0; h < 2; h++) {
    if (h) __syncthreads();            // conv(h-1) finished reading LDS

    // ---- phase A half h: per wave 4 samples; weights recomputed per half ----
    for (int i = 0; i < 4; i++) {
      const int s = w*4 + i;
      uint2 dj[8];
      u32 apk[4];                      // statically indexed, local to this i
      float wvp = 0.f;
#pragma unroll
      for (int j = 0; j < 8; j++) {
        float4 mje = meta[s*32 + lg*8 + j];
        u32 off = __builtin_bit_cast(u32, mje.w);
        dj[j] = *(const uint2*)(fb + off + h*128 + lr*8);
        float ex = mje.x - kx, ey = mje.y - ky, ez = mje.z - kz;
        float d = sqrtf(ex*ex + ey*ey + ez*ez);
        float wv = kvalid ? fmaxf(1.f - d * inv_ext, 0.f) : 0.f;
        if (j & 1) apk[j>>1] = f2bf(wvp) | (f2bf(wv) << 16);
        else       wvp = wv;
      }
      u32x4 av = {apk[0], apk[1], apk[2], apk[3]};
      bf16x8 afr = __builtin_bit_cast(bf16x8, av);

      f32x4 D[4];
#pragma unroll
      for (int q = 0; q < 4; q++) {
        u32 b[4];
#pragma unroll
        for (int u = 0; u < 4; u++) {
          u32 w0 = (q < 2) ? dj[2*u].x   : dj[2*u].y;
          u32 w1 = (q < 2) ? dj[2*u+1].x : dj[2*u+1].y;
          b[u] = __builtin_amdgcn_perm(w1, w0, (q & 1) ? 0x07060302u : 0x05040100u);
        }
        u32x4 bv = {b[0], b[1], b[2], b[3]};
        D[q] = __builtin_amdgcn_mfma_f32_16x16x32_bf16(
                   afr, __builtin_bit_cast(bf16x8, bv), zero, 0,0,0);
      }
      char* wrow = smem + s * WROWB;
      const int sswz = (s & 7) << 4;
#pragma unroll
      for (int r = 0; r < 4; r++) {
        int kr = lg*4 + r;
        if (kr < KKP) {
          uint2 pv;
          pv.x = f2bf(D[0][r]) | (f2bf(D[1][r]) << 16);
          pv.y = f2bf(D[2][r]) | (f2bf(D[3][r]) << 16);
          *(uint2*)(wrow + ((kr*128 + lr*8) ^ sswz)) = pv;
        }
      }
    }
    __syncthreads();

    // ---- conv half h: wave = o-tile w; A broadcast from LDS, B direct from L2 ----
    const char* bb = (const char*)bpack + (size_t)(h*240 + w) * 1024 + lr*64 + lg*16;
#pragma unroll 6
    for (int s = 0; s < 30; s++) {
      int aoff = (s*64 + lg*16) ^ convswz;
      bf16x8 af0 = *(const bf16x8*)(arow0 + aoff);
      bf16x8 af1 = *(const bf16x8*)(arow1 + aoff);
      bf16x8 bfr = *(const bf16x8*)(bb + s*8192);
      acc[0] = __builtin_amdgcn_mfma_f32_16x16x32_bf16(af0, bfr, acc[0], 0,0,0);
      acc[1] = __builtin_amdgcn_mfma_f32_16x16x32_bf16(af1, bfr, acc[1], 0,0,0);
    }
  }
  __syncthreads();                     // conv done; wfeat region reusable

  // ---- epilogue staging: a2 = leaky(conv) bf16 swz; a3 = raw feats bf16 swz ----
  char* a2 = smem + A2_OFF;
  char* a3 = smem + A3_OFF;
#pragma unroll
  for (int mi = 0; mi < 2; mi++)
#pragma unroll
  for (int r = 0; r < 4; r++) {
    int m = mi*16 + lg*4 + r;
    int o = w*16 + lr;
    *(unsigned short*)(a2 + m*256 + ((o*2) ^ ((m & 15) << 4))) =
        (unsigned short)f2bf(leaky(acc[mi][r]));
  }
  if (t < 256) {
    int r = t >> 3, seg = t & 7;
    int sidx = sample_idx[m0 + r];
    const float* src = features + (size_t)sidx * INF + seg*8;
    float4 f0 = *(const float4*)src, f1 = *(const float4*)(src + 4);
    uint4 pv = make_uint4(f2bf(f0.x) | (f2bf(f0.y) << 16),
                          f2bf(f0.z) | (f2bf(f0.w) << 16),
                          f2bf(f1.x) | (f2bf(f1.y) << 16),
                          f2bf(f1.z) | (f2bf(f1.w) << 16));
    *(uint4*)(a3 + r*128 + ((seg*16) ^ ((r & 7) << 4))) = pv;
  }
  __syncthreads();

  // ---- post (K=128) + shortcut (K=64): wave = (mt, oq), biases in C init ----
  const int mt = w & 1, oq = w >> 1;
  const int mrow = mt*16 + lr;
  f32x4 d[2];
#pragma unroll
  for (int ot = 0; ot < 2; ot++) {
    float bv = bpost[oq*32 + ot*16 + lr] + bsc[oq*32 + ot*16 + lr];
    d[ot] = (f32x4){bv, bv, bv, bv};
  }
#pragma unroll
  for (int ks = 0; ks < 4; ks++) {
    bf16x8 af = *(const bf16x8*)(a2 + mrow*256 + ((ks*64 + lg*16) ^ ((mrow & 15) << 4)));
#pragma unroll
    for (int ot = 0; ot < 2; ot++) {
      bf16x8 b = *(const bf16x8*)(wpostT + (size_t)(oq*32 + ot*16 + lr) * OUTF + ks*32 + lg*8);
      d[ot] = __builtin_amdgcn_mfma_f32_16x16x32_bf16(af, b, d[ot], 0,0,0);
    }
  }
#pragma unroll
  for (int ks = 0; ks < 2; ks++) {
    bf16x8 af = *(const bf16x8*)(a3 + mrow*128 + ((ks*64 + lg*16) ^ ((mrow & 7) << 4)));
#pragma unroll
    for (int ot = 0; ot < 2; ot++) {
      bf16x8 b = *(const bf16x8*)(wscT + (size_t)(oq*32 + ot*16 + lr) * INF + ks*32 + lg*8);
      d[ot] = __builtin_amdgcn_mfma_f32_16x16x32_bf16(af, b, d[ot], 0,0,0);
    }
  }
#pragma unroll
  for (int ot = 0; ot < 2; ot++)
#pragma unroll
  for (int r = 0; r < 4; r++) {
    int m = mt*16 + lg*4 + r;
    int o = oq*32 + ot*16 + lr;
    out[(size_t)(m0 + m) * OUTF + o] = leaky(d[ot][r]);
  }
}

extern "C" void kernel_launch(void* const* d_in, const int* in_sizes, int n_in,
                              void* d_out, int out_size, void* d_ws, size_t ws_size,
                              hipStream_t stream)
{
  const float* points   = (const float*)d_in[0];
  const float* features = (const float*)d_in[1];
  const float* W_pre    = (const float*)d_in[2];
  const float* b_pre    = (const float*)d_in[3];
  const float* kpts     = (const float*)d_in[4];
  const float* kpw      = (const float*)d_in[5];
  const float* W_post   = (const float*)d_in[6];
  const float* b_post   = (const float*)d_in[7];
  const float* W_sc     = (const float*)d_in[8];
  const float* b_sc     = (const float*)d_in[9];
  const int* sample_idx = (const int*)d_in[10];
  const int* nbr        = (const int*)d_in[11];
  float* out = (float*)d_out;

  char* ws = (char*)d_ws;
  unsigned short* featbf = (unsigned short*)ws;                 // 33,554,432 B
  unsigned short* bpack  = (unsigned short*)(ws + 33554432);    //    491,520 B
  unsigned short* wpostT = (unsigned short*)(ws + 34045952);    //     32,768 B
  unsigned short* wscT   = (unsigned short*)(ws + 34078720);    //     16,384 B
  unsigned short* wpreT  = (unsigned short*)(ws + 34095104);    //     16,384 B

  double ext = (1.5 / 40.0) / (pow(15.0, 1.0 / 3.0) - 1.0) * 1.5;
  float inv_ext = (float)(1.0 / ext);

  (void)hipFuncSetAttribute((const void*)k_fused_67723,
                            hipFuncAttributeMaxDynamicSharedMemorySize, LDS_TOTAL);

  const int nwg = MTOT / 32;   // 2048
  k_cvt_67723<<<1088, 256, 0, stream>>>(kpw, W_post, W_sc, W_pre, bpack, wpostT, wscT, wpreT);
  k_pre_67723<<<1024, 256, 0, stream>>>(features, wpreT, b_pre, featbf);
  k_fused_67723<<<nwg, 512, LDS_TOTAL, stream>>>(points, features, kpts, b_post, b_sc,
                                                 sample_idx, nbr, featbf, bpack, wpostT,
                                                 wscT, out, inv_ext, nwg);
}